// Round 7
// baseline (1271.846 us; speedup 1.0000x reference)
//
#include <hip/hip_runtime.h>
#include <stdint.h>

#define NUTT 2048
#define NNODE 2304
#define NE 8128

typedef __attribute__((ext_vector_type(8))) short short8;
typedef __attribute__((ext_vector_type(16))) float float16;

__device__ __forceinline__ float16 MFMA(short8 a, short8 b, float16 c) {
  return __builtin_amdgcn_mfma_f32_32x32x16_bf16(a, b, c, 0, 0, 0);
}

__device__ __forceinline__ unsigned short f2b(float f) {
  unsigned int u = __builtin_bit_cast(unsigned int, f);
  u = (u + 0x7FFFu + ((u >> 16) & 1u)) >> 16;
  return (unsigned short)u;
}
__device__ __forceinline__ float b2f(unsigned short h) {
  unsigned int u = ((unsigned int)h) << 16;
  return __builtin_bit_cast(float, u);
}

// ---------------- workspace offsets (bytes) ----------------
#define OFF_WW   0u
#define OFF_BCNN 19200000u   // 466944 bf16 = 933888 B (region reserves 983040)
#define OFF_BGAT 20183040u
#define OFF_BSA  29521920u
#define OFF_BPA  29716480u
#define OFF_WX   29911040u
#define OFF_H16  32368640u   // [2304][312] bf16 (624B rows, cols 300..311 zero)
#define OFF_Z    33806336u   // [2304][3072] bf16 (cols 0..1499 fc, 1500..2999 res)
#define OFF_EL   47962112u
#define OFF_ER   48008192u
#define OFF_CNT  48054272u
#define OFF_CUR  48063488u
#define OFF_PTR  48072704u
#define OFF_EID  48082176u

// ---------------- packing kernels ----------------
__global__ void pack_wordW(const float* __restrict__ src, unsigned short* __restrict__ dst) {
  int i4 = (blockIdx.x * 256 + threadIdx.x) * 4;
  if (i4 >= 9600000) return;
  const float4 v = *(const float4*)(src + i4);
  uint2 o;
  o.x = (unsigned int)f2b(v.x) | ((unsigned int)f2b(v.y) << 16);
  o.y = (unsigned int)f2b(v.z) | ((unsigned int)f2b(v.w) << 16);
  *(uint2*)(dst + i4) = o;
}

// CNN B pack: per section, [4 nt-tiles][KS=19*W k-steps][512 lane-elems],
// k = ks*16 + 8*(lane>>5) + j ; tap = k/304, koff = k%304 (300..303 zero)
__global__ void pack_cnnB(const float* __restrict__ w3, const float* __restrict__ w4,
                          const float* __restrict__ w5, unsigned short* __restrict__ out) {
  int i = blockIdx.x * 256 + threadIdx.x;
  if (i >= 466944) return;
  int width, local; const float* cw;
  if (i < 116736)      { width = 3; local = i;          cw = w3; }
  else if (i < 272384) { width = 4; local = i - 116736; cw = w4; }
  else                 { width = 5; local = i - 272384; cw = w5; }
  int KS = 19 * width;
  int per_nt = KS * 512;
  int nt = local / per_nt;
  int rem = local - nt * per_nt;
  int ks = rem >> 9;
  int lr = rem & 511;
  int lane = lr >> 3, j = lr & 7;
  int col = nt * 32 + (lane & 31);
  int k = ks * 16 + 8 * (lane >> 5) + j;
  int tap = k / 304, koff = k - tap * 304;
  float v = 0.f;
  if (col < 100 && koff < 300) v = cw[(col * width + tap) * 300 + koff];
  out[i] = f2b(v);
}

__global__ void pack_gatB(const float* __restrict__ fc, const float* __restrict__ res,
                          unsigned short* __restrict__ out) {
  int i = blockIdx.x * 256 + threadIdx.x;
  if (i >= 4669440) return;
  int layer = i / 933888;
  int rem = i - layer * 933888;
  int nt = rem / (19 * 512);
  int r2 = rem - nt * (19 * 512);
  int ks = r2 >> 9;
  int lr = r2 & 511;
  int lane = lr >> 3, j = lr & 7;
  int col = nt * 32 + (lane & 31);
  int k = ks * 16 + 8 * (lane >> 5) + j;
  float v = 0.f;
  if (k < 300) {
    if (col < 1500)      v = fc[((size_t)layer * 300 + k) * 1500 + col];
    else if (col < 3000) v = res[((size_t)layer * 300 + k) * 1500 + (col - 1500)];
  }
  out[i] = f2b(v);
}

__global__ void pack_poolB(const float* __restrict__ W, unsigned short* __restrict__ out) {
  int i = blockIdx.x * 256 + threadIdx.x;
  if (i >= 97280) return;
  int nt = i / (19 * 512);
  int r2 = i - nt * (19 * 512);
  int ks = r2 >> 9;
  int lr = r2 & 511;
  int lane = lr >> 3, j = lr & 7;
  int col = nt * 32 + (lane & 31);
  int k = ks * 16 + 8 * (lane >> 5) + j;
  float v = 0.f;
  if (k < 300 && col < 300) v = W[k * 300 + col];
  out[i] = f2b(v);
}

// ---------------- CSR build ----------------
__global__ void csr_zero(int* cnt, int* cur) {
  int i = blockIdx.x * 256 + threadIdx.x;
  if (i < NNODE) { cnt[i] = 0; cur[i] = 0; }
}
__global__ void csr_count(const int* __restrict__ dst, int* cnt) {
  int e = blockIdx.x * 256 + threadIdx.x;
  if (e < NE) atomicAdd(&cnt[dst[e]], 1);
}
__global__ void csr_scan(const int* __restrict__ cnt, int* __restrict__ ptr) {
  __shared__ int part[256];
  __shared__ int loc[NNODE];
  int t = threadIdx.x;
  int s = 0;
  for (int k = 0; k < 9; ++k) { loc[t * 9 + k] = s; s += cnt[t * 9 + k]; }
  part[t] = s;
  __syncthreads();
  for (int off = 1; off < 256; off <<= 1) {
    int add = (t >= off) ? part[t - off] : 0;
    __syncthreads();
    part[t] += add;
    __syncthreads();
  }
  int base = part[t] - s;
  for (int k = 0; k < 9; ++k) ptr[t * 9 + k] = base + loc[t * 9 + k];
  if (t == 255) ptr[NNODE] = part[255];
}
__global__ void csr_scatter(const int* __restrict__ dst, const int* __restrict__ ptr,
                            int* cur, int* __restrict__ eid) {
  int e = blockIdx.x * 256 + threadIdx.x;
  if (e < NE) {
    int d = dst[e];
    int pos = atomicAdd(&cur[d], 1);
    eid[ptr[d] + pos] = e;
  }
}

// ---------------- CNN ----------------
// LDS: A [256 rows][624 B stride] = 159744 (odd multiple of 16 -> conflict-free)
// scratch 8 waves * 64 f32 @159744 -> 161792
// 8 waves = 4 Mblk (64 rows) x 2 nt-pairs (64 cols). Wave: acc[2M][2N].
// BOTH operand streams software-pipelined:
//  - B: depth-6 register ring (global, ~200cyc L2 latency covered)
//  - A: 1-step-ahead register prefetch (ds_read ~120cyc latency hidden
//    under the current step's 4 MFMAs). 2 waves/SIMD can't hide
//    just-in-time ds_reads on their own (R6: 32.6% MfmaUtil).
template<int W, int WSEC>
__device__ __forceinline__ void cnn_section(const char* sm, float* scratch,
    const unsigned short* Bsec, const float* bias, float* wxrow, int tid) {
  const int KS = 19 * W;
  const int PD = 6;   // B prefetch depth
  int lane = tid & 63, wave = tid >> 6;
  int l31 = lane & 31, g = lane >> 5;
  int Mblk = wave >> 1, ntp = wave & 1;
  float16 acc[2][2] = {};
  const char* bbase = (const char*)Bsec + (size_t)(ntp * 2 * KS) * 1024 + lane * 16;
  short8 pb0[PD], pb1[PD];
  #pragma unroll
  for (int p = 0; p < PD; ++p) {
    pb0[p] = *(const short8*)(bbase + (size_t)p * 1024);
    pb1[p] = *(const short8*)(bbase + (size_t)(KS + p) * 1024);
  }
  int rbase = Mblk * 64 + l31;
  int kbg = 16 * g;
  // row byte-offset for tap j, sub-block add (row clamp: last Mblk's tail
  // rows read row 255; results masked by row <= 256-W below)
  auto arow = [&](int j, int add) {
    int q = rbase + add + j;
    return (q > 255 ? 255 : q) * 624;
  };
  short8 a0c = *(const short8*)(sm + arow(0, 0) + kbg);
  short8 a1c = *(const short8*)(sm + arow(0, 32) + kbg);
  short8 a0n = a0c, a1n = a1c;
  #pragma unroll
  for (int t = 0; t < KS; ++t) {
    // prefetch A for step t+1 (in flight across this step's MFMAs)
    if (t + 1 < KS) {
      const int j1 = (t + 1) / 19, kl1 = (t + 1) % 19;
      a0n = *(const short8*)(sm + arow(j1, 0) + kl1 * 32 + kbg);
      a1n = *(const short8*)(sm + arow(j1, 32) + kl1 * 32 + kbg);
    }
    short8 b0 = pb0[t % PD];
    short8 b1 = pb1[t % PD];
    if (t + PD < KS) {
      pb0[t % PD] = *(const short8*)(bbase + (size_t)(t + PD) * 1024);
      pb1[t % PD] = *(const short8*)(bbase + (size_t)(KS + t + PD) * 1024);
    }
    acc[0][0] = MFMA(a0c, b0, acc[0][0]);
    acc[0][1] = MFMA(a0c, b1, acc[0][1]);
    acc[1][0] = MFMA(a1c, b0, acc[1][0]);
    acc[1][1] = MFMA(a1c, b1, acc[1][1]);
    a0c = a0n; a1c = a1n;
  }
  // col = ntp*64 + ni*32 + l31 ; row = Mblk*64 + mi*32 + (r&3)+8*(r>>2)+4*g
  float cm0 = -3.0e38f, cm1 = -3.0e38f;
  #pragma unroll
  for (int mi = 0; mi < 2; ++mi) {
    #pragma unroll
    for (int r = 0; r < 16; ++r) {
      int row = Mblk * 64 + mi * 32 + (r & 3) + 8 * (r >> 2) + 4 * g;
      if (row <= 256 - W) {
        float v0 = acc[mi][0][r], v1 = acc[mi][1][r];
        if (v0 > cm0) cm0 = v0;
        if (v1 > cm1) cm1 = v1;
      }
    }
  }
  cm0 = fmaxf(cm0, __shfl_xor(cm0, 32));
  cm1 = fmaxf(cm1, __shfl_xor(cm1, 32));
  if (lane < 32) {
    scratch[wave * 64 + l31]      = cm0;
    scratch[wave * 64 + 32 + l31] = cm1;
  }
  __syncthreads();
  if (tid < 128) {
    int f = tid;
    if (f < 100) {
      int ntp_f = f >> 6, rest = f & 63;   // f = ntp*64 + ni*32 + c
      float v =        scratch[(0 * 2 + ntp_f) * 64 + rest];
      v = fmaxf(v,     scratch[(1 * 2 + ntp_f) * 64 + rest]);
      v = fmaxf(v,     scratch[(2 * 2 + ntp_f) * 64 + rest]);
      v = fmaxf(v,     scratch[(3 * 2 + ntp_f) * 64 + rest]);
      wxrow[WSEC * 100 + f] = v + bias[f];
    }
  }
  __syncthreads();
}

__global__ __launch_bounds__(512, 2) void cnn_kernel(
    const int* __restrict__ x, const unsigned short* __restrict__ wW,
    const unsigned short* __restrict__ Bcnn,
    const float* __restrict__ cb3, const float* __restrict__ cb4, const float* __restrict__ cb5,
    float* __restrict__ wx) {
  extern __shared__ char sm[];
  int n = blockIdx.x, tid = threadIdx.x;
  float* scratch = (float*)(sm + 159744);
  const int* xr = x + n * 256;
  for (int i = tid; i < 19968; i += 512) {   // 256 rows * 78 chunks (8B) = 624 B/row
    int r = i / 78, c = i - r * 78;
    uint2 v; v.x = 0u; v.y = 0u;
    if (c < 75) {
      int tok = xr[r];
      v = *(const uint2*)((const char*)wW + (size_t)tok * 600 + c * 8);
    }
    *(uint2*)(sm + r * 624 + c * 8) = v;
  }
  __syncthreads();
  float* wxrow = wx + (size_t)n * 300;
  cnn_section<3, 0>(sm, scratch, Bcnn,           cb3, wxrow, tid);
  cnn_section<4, 1>(sm, scratch, Bcnn + 116736,  cb4, wxrow, tid);
  cnn_section<5, 2>(sm, scratch, Bcnn + 272384,  cb5, wxrow, tid);
}

// ---------------- feature assembly ----------------
__global__ void feat_kernel(const float* __restrict__ wx, const float* __restrict__ posW,
                            const int* __restrict__ lid, const float* __restrict__ partyW,
                            const int* __restrict__ pids, const int* __restrict__ u_idx,
                            const int* __restrict__ q_idx, unsigned short* __restrict__ h16) {
  int b = blockIdx.x, t = threadIdx.x;
  int node = (b < NUTT) ? u_idx[b] : q_idx[b - NUTT];
  for (int d = t; d < 312; d += 64) {
    float v = 0.f;
    if (d < 300)
      v = (b < NUTT) ? (wx[(size_t)b * 300 + d] + posW[(size_t)lid[b] * 300 + d])
                     : partyW[(size_t)pids[b - NUTT] * 300 + d];
    h16[(size_t)node * 312 + d] = (d < 300) ? f2b(v) : (unsigned short)0;
  }
}

// ---------------- GAT GEMM: z|res = h @ [fc|res] ----------------
__global__ __launch_bounds__(512, 2) void gat_mm(
    const unsigned short* __restrict__ h16, const unsigned short* __restrict__ Bg,
    unsigned short* __restrict__ z) {
  extern __shared__ char sm[];   // 128 rows * 624B = 79872
  int tid = threadIdx.x, lane = tid & 63, wave = tid >> 6;
  int WGm = blockIdx.x, WGn = blockIdx.y;
  const char* srcp = (const char*)h16 + (size_t)WGm * 79872;
  for (int i = tid; i < 4992; i += 512)
    *(uint4*)(sm + i * 16) = *(const uint4*)(srcp + (size_t)i * 16);
  __syncthreads();
  int l31 = lane & 31, g = lane >> 5;
  int Mblk = wave >> 2, Nblk = wave & 3;
  float16 acc[2][2] = {};
  const char* a0 = sm + (Mblk * 64 + l31) * 624 + 16 * g;
  const char* a1 = a0 + 32 * 624;
  const char* b0 = (const char*)Bg + (size_t)((WGn * 8 + Nblk * 2) * 19) * 1024 + lane * 16;
  const char* b1 = b0 + 19 * 1024;
  #pragma unroll 2
  for (int ks = 0; ks < 19; ++ks) {
    short8 A0 = *(const short8*)(a0 + ks * 32);
    short8 A1 = *(const short8*)(a1 + ks * 32);
    short8 B0 = *(const short8*)(b0 + (size_t)ks * 1024);
    short8 B1 = *(const short8*)(b1 + (size_t)ks * 1024);
    acc[0][0] = MFMA(A0, B0, acc[0][0]);
    acc[0][1] = MFMA(A0, B1, acc[0][1]);
    acc[1][0] = MFMA(A1, B0, acc[1][0]);
    acc[1][1] = MFMA(A1, B1, acc[1][1]);
  }
  #pragma unroll
  for (int mi = 0; mi < 2; ++mi)
    #pragma unroll
    for (int ni = 0; ni < 2; ++ni)
      #pragma unroll
      for (int r = 0; r < 16; ++r) {
        int row = WGm * 128 + Mblk * 64 + mi * 32 + (r & 3) + 8 * (r >> 2) + 4 * g;
        int col = WGn * 256 + (Nblk * 2 + ni) * 32 + l31;
        z[(size_t)row * 3072 + col] = f2b(acc[mi][ni][r]);
      }
}

// ---------------- GAT edge kernels ----------------
__global__ void gat_edge1(const unsigned short* __restrict__ z,
                          const float* __restrict__ al, const float* __restrict__ ar,
                          float* __restrict__ el, float* __restrict__ er) {
  int node = blockIdx.x * 4 + (threadIdx.x >> 6);
  if (node >= NNODE) return;
  int lane = threadIdx.x & 63;
  for (int h = 0; h < 5; ++h) {
    float accl = 0.f, accr = 0.f;
    for (int d = lane; d < 300; d += 64) {
      float zv = b2f(z[(size_t)node * 3072 + h * 300 + d]);
      accl += zv * al[h * 300 + d];
      accr += zv * ar[h * 300 + d];
    }
    for (int s = 32; s; s >>= 1) {
      accl += __shfl_xor(accl, s);
      accr += __shfl_xor(accr, s);
    }
    if (lane == 0) { el[node * 5 + h] = accl; er[node * 5 + h] = accr; }
  }
}

__global__ __launch_bounds__(320) void gat_edge2(
    const unsigned short* __restrict__ z, const float* __restrict__ el,
    const float* __restrict__ er, const float* __restrict__ gb,
    const int* __restrict__ ptr, const int* __restrict__ eidl,
    const int* __restrict__ srcA, unsigned short* __restrict__ h16out) {
  int dstn = blockIdx.x;
  int tid = threadIdx.x, h = tid >> 6, lane = tid & 63;
  __shared__ float lds5[5][304];
  int p0 = ptr[dstn], deg = ptr[dstn + 1] - p0;
  float ee = 0.f, den = 0.f;
  int sj = 0;
  if (deg > 0) {
    float s = -3.0e38f;
    if (lane < deg) {
      int e = eidl[p0 + lane];
      sj = srcA[e];
      float sv = el[sj * 5 + h] + er[dstn * 5 + h];
      s = (sv >= 0.f) ? sv : 0.2f * sv;
    }
    float m = s;
    for (int t = 32; t; t >>= 1) m = fmaxf(m, __shfl_xor(m, t));
    ee = (lane < deg) ? __expf(s - m) : 0.f;
    den = ee;
    for (int t = 32; t; t >>= 1) den += __shfl_xor(den, t);
  }
  for (int it = 0; it < 5; ++it) {
    int d = lane + it * 64;
    float acc = 0.f;
    if (deg > 0) {
      for (int e = 0; e < deg; ++e) {
        float w = __shfl(ee, e);
        int srow = __shfl(sj, e);
        if (d < 300) acc += w * b2f(z[(size_t)srow * 3072 + h * 300 + d]);
      }
      acc /= den;
    }
    if (d < 300) {
      float res = b2f(z[(size_t)dstn * 3072 + 1500 + h * 300 + d]);
      lds5[h][d] = acc + res + gb[h * 300 + d];
    }
  }
  __syncthreads();
  if (tid < 312) {
    float v = 0.f;
    if (tid < 300)
      v = 0.2f * (lds5[0][tid] + lds5[1][tid] + lds5[2][tid] + lds5[3][tid] + lds5[4][tid]);
    h16out[(size_t)dstn * 312 + tid] = (tid < 300) ? f2b(v) : (unsigned short)0;
  }
}

// ---------------- pooling + head ----------------
__device__ __forceinline__ void ctx_attn(const char* XB, int mtiles, int Kvalid,
    const unsigned short* Bw, const float* bias, const float* cvec,
    float* T, float* AA, float* OUT, int tid) {
  int lane = tid & 63, wave = tid >> 6;
  int l31 = lane & 31, g = lane >> 5;
  int ntasks = mtiles * 10;
  for (int t = wave; t < ntasks; t += 8) {
    int nt, mt;
    if (mtiles == 2) { nt = t >> 1; mt = t & 1; } else { nt = t; mt = 0; }
    float16 acc = {};
    const char* ap = XB + (mt * 32 + l31) * 624 + 16 * g;
    const char* bp = (const char*)Bw + (size_t)(nt * 19) * 1024 + lane * 16;
    for (int ks = 0; ks < 19; ++ks) {
      short8 A = *(const short8*)(ap + ks * 32);
      short8 Bv = *(const short8*)(bp + (size_t)ks * 1024);
      acc = MFMA(A, Bv, acc);
    }
    int col = nt * 32 + l31;
    if (col < 300) {
      float bc = bias[col];
      #pragma unroll
      for (int r = 0; r < 16; ++r) {
        int row = mt * 32 + (r & 3) + 8 * (r >> 2) + 4 * g;
        T[row * 305 + col] = tanhf(acc[r] + bc);
      }
    }
  }
  __syncthreads();
  if (tid < 64) {
    float lg = -3.0e38f;
    if (tid < Kvalid) {
      lg = 0.f;
      for (int d = 0; d < 300; ++d) lg += T[tid * 305 + d] * cvec[d];
    }
    AA[tid] = lg;
  }
  __syncthreads();
  if (wave == 0) {
    float v = AA[lane];
    float m = v;
    for (int s2 = 32; s2; s2 >>= 1) m = fmaxf(m, __shfl_xor(m, s2));
    float e = (lane < Kvalid) ? __expf(v - m) : 0.f;
    float s = e;
    for (int s2 = 32; s2; s2 >>= 1) s += __shfl_xor(s, s2);
    AA[lane] = e / s;
  }
  __syncthreads();
  if (tid < 300) {
    float acc = 0.f;
    for (int k = 0; k < Kvalid; ++k)
      acc += AA[k] * b2f(*(const unsigned short*)(XB + k * 624 + tid * 2));
    OUT[tid] = acc;
  }
  __syncthreads();
}

__global__ __launch_bounds__(512) void pool_kernel(
    const unsigned short* __restrict__ h16,
    const int* __restrict__ u_idx, const int* __restrict__ q_idx,
    const float* __restrict__ py,
    const unsigned short* __restrict__ Bsa, const unsigned short* __restrict__ Bpa,
    const float* __restrict__ sab, const float* __restrict__ sac,
    const float* __restrict__ pab, const float* __restrict__ pac,
    const float* __restrict__ vW, const float* __restrict__ vb,
    const float* __restrict__ outW, const float* __restrict__ outb,
    float* __restrict__ dout) {
  extern __shared__ char sm[];
  int b = blockIdx.x, tid = threadIdx.x;
  char* HU = sm;                       // 39936
  char* HQ = sm + 39936;               // 19968 -> 59904
  float* T   = (float*)(sm + 59904);   // 64*305*4 = 78080 -> 137984
  float* AA  = (float*)(sm + 137984);  // 256 -> 138240
  float* PX  = (float*)(sm + 138240);  // 1216 -> 139456
  float* SX  = (float*)(sm + 139456);  // 1216 -> 140672
  float* RED = (float*)(sm + 140672);  // 2048 -> 142720
  for (int i = tid; i < 64 * 78; i += 512) {
    int r = i / 78, c = i - r * 78;
    int node = u_idx[b * 64 + r];
    *(uint2*)(HU + r * 624 + c * 8) =
        *(const uint2*)((const char*)h16 + (size_t)node * 624 + c * 8);
  }
  for (int i = tid; i < 32 * 78; i += 512) {
    int r = i / 78, c = i - r * 78;
    uint2 v; v.x = 0u; v.y = 0u;
    if (r < 8) {
      int node = q_idx[b * 8 + r];
      v = *(const uint2*)((const char*)h16 + (size_t)node * 624 + c * 8);
    }
    *(uint2*)(HQ + r * 624 + c * 8) = v;
  }
  __syncthreads();
  ctx_attn(HU, 2, 64, Bsa, sab, sac, T, AA, SX, tid);
  ctx_attn(HQ, 1, 8,  Bpa, pab, pac, T, AA, PX, tid);
  float contrib = 0.f;
  if (tid < 300) {
    float pv = py[b] * vW[tid] + vb[tid];
    contrib = PX[tid] * outW[tid] + SX[tid] * outW[300 + tid] + pv * outW[600 + tid];
  }
  RED[tid] = contrib;
  __syncthreads();
  for (int s = 256; s > 0; s >>= 1) {
    if (tid < s) RED[tid] += RED[tid + s];
    __syncthreads();
  }
  if (tid == 0) dout[b] = RED[0] + outb[0];
}

// ---------------- launcher ----------------
extern "C" void kernel_launch(void* const* d_in, const int* in_sizes, int n_in,
                              void* d_out, int out_size, void* d_ws, size_t ws_size,
                              hipStream_t stream) {
  (void)in_sizes; (void)n_in; (void)out_size; (void)ws_size;
  const int*   x       = (const int*)d_in[0];
  const int*   srcA    = (const int*)d_in[1];
  const int*   dstA    = (const int*)d_in[2];
  const int*   u_idx   = (const int*)d_in[3];
  const int*   q_idx   = (const int*)d_in[4];
  const int*   lid     = (const int*)d_in[5];
  const int*   pids    = (const int*)d_in[6];
  const float* py      = (const float*)d_in[7];
  const float* word_W  = (const float*)d_in[8];
  const float* cw3     = (const float*)d_in[9];
  const float* cb3     = (const float*)d_in[10];
  const float* cw4     = (const float*)d_in[11];
  const float* cb4     = (const float*)d_in[12];
  const float* cw5     = (const float*)d_in[13];
  const float* cb5     = (const float*)d_in[14];
  const float* party_W = (const float*)d_in[15];
  const float* pos_W   = (const float*)d_in[16];
  const float* gat_fc  = (const float*)d_in[17];
  const float* gat_al  = (const float*)d_in[18];
  const float* gat_ar  = (const float*)d_in[19];
  const float* gat_res = (const float*)d_in[20];
  const float* gat_b   = (const float*)d_in[21];
  const float* pa_W    = (const float*)d_in[22];
  const float* pa_b    = (const float*)d_in[23];
  const float* pa_c    = (const float*)d_in[24];
  const float* sa_W    = (const float*)d_in[25];
  const float* sa_b    = (const float*)d_in[26];
  const float* sa_c    = (const float*)d_in[27];
  const float* v_W     = (const float*)d_in[28];
  const float* v_b     = (const float*)d_in[29];
  const float* out_W   = (const float*)d_in[30];
  const float* out_b   = (const float*)d_in[31];

  char* ws = (char*)d_ws;
  unsigned short* wW16 = (unsigned short*)(ws + OFF_WW);
  unsigned short* Bcnn = (unsigned short*)(ws + OFF_BCNN);
  unsigned short* Bgat = (unsigned short*)(ws + OFF_BGAT);
  unsigned short* Bsa  = (unsigned short*)(ws + OFF_BSA);
  unsigned short* Bpa  = (unsigned short*)(ws + OFF_BPA);
  float*          wx   = (float*)(ws + OFF_WX);
  unsigned short* h16  = (unsigned short*)(ws + OFF_H16);
  unsigned short* z    = (unsigned short*)(ws + OFF_Z);
  float*          el   = (float*)(ws + OFF_EL);
  float*          er   = (float*)(ws + OFF_ER);
  int*            cnt  = (int*)(ws + OFF_CNT);
  int*            cur  = (int*)(ws + OFF_CUR);
  int*            ptr  = (int*)(ws + OFF_PTR);
  int*            eid  = (int*)(ws + OFF_EID);

  (void)hipFuncSetAttribute((const void*)cnn_kernel,
      hipFuncAttributeMaxDynamicSharedMemorySize, 161792);
  (void)hipFuncSetAttribute((const void*)gat_mm,
      hipFuncAttributeMaxDynamicSharedMemorySize, 79872);
  (void)hipFuncSetAttribute((const void*)pool_kernel,
      hipFuncAttributeMaxDynamicSharedMemorySize, 142720);

  pack_wordW<<<dim3(9375), dim3(256), 0, stream>>>(word_W, wW16);
  pack_cnnB<<<dim3(1824), dim3(256), 0, stream>>>(cw3, cw4, cw5, Bcnn);
  pack_gatB<<<dim3(18240), dim3(256), 0, stream>>>(gat_fc, gat_res, Bgat);
  pack_poolB<<<dim3(380), dim3(256), 0, stream>>>(sa_W, Bsa);
  pack_poolB<<<dim3(380), dim3(256), 0, stream>>>(pa_W, Bpa);

  csr_zero<<<dim3(9), dim3(256), 0, stream>>>(cnt, cur);
  csr_count<<<dim3(32), dim3(256), 0, stream>>>(dstA, cnt);
  csr_scan<<<dim3(1), dim3(256), 0, stream>>>(cnt, ptr);
  csr_scatter<<<dim3(32), dim3(256), 0, stream>>>(dstA, ptr, cur, eid);

  cnn_kernel<<<dim3(2048), dim3(512), 161792, stream>>>(x, wW16, Bcnn, cb3, cb4, cb5, wx);
  feat_kernel<<<dim3(NNODE), dim3(64), 0, stream>>>(wx, pos_W, lid, party_W, pids,
                                                    u_idx, q_idx, h16);
  for (int l = 0; l < 5; ++l) {
    gat_mm<<<dim3(18, 12), dim3(512), 79872, stream>>>(h16, Bgat + (size_t)l * 933888, z);
    gat_edge1<<<dim3(576), dim3(256), 0, stream>>>(z, gat_al + l * 1500, gat_ar + l * 1500,
                                                   el, er);
    gat_edge2<<<dim3(NNODE), dim3(320), 0, stream>>>(z, el, er, gat_b + l * 1500,
                                                     ptr, eid, srcA, h16);
  }
  pool_kernel<<<dim3(32), dim3(512), 142720, stream>>>(
      h16, u_idx, q_idx, py, Bsa, Bpa, sa_b, sa_c, pa_b, pa_c,
      v_W, v_b, out_W, out_b, (float*)d_out);
}

// Round 8
// 1131.007 us; speedup vs baseline: 1.1245x; 1.1245x over previous
//
#include <hip/hip_runtime.h>
#include <stdint.h>

#define NUTT 2048
#define NNODE 2304
#define NE 8128

typedef __attribute__((ext_vector_type(8))) short short8;
typedef __attribute__((ext_vector_type(16))) float float16;

__device__ __forceinline__ float16 MFMA(short8 a, short8 b, float16 c) {
  return __builtin_amdgcn_mfma_f32_32x32x16_bf16(a, b, c, 0, 0, 0);
}

__device__ __forceinline__ unsigned short f2b(float f) {
  unsigned int u = __builtin_bit_cast(unsigned int, f);
  u = (u + 0x7FFFu + ((u >> 16) & 1u)) >> 16;
  return (unsigned short)u;
}
__device__ __forceinline__ float b2f(unsigned short h) {
  unsigned int u = ((unsigned int)h) << 16;
  return __builtin_bit_cast(float, u);
}

// ---------------- workspace offsets (bytes) ----------------
#define OFF_WW   0u
#define OFF_BCNN 19200000u   // 466944 bf16 = 933888 B
#define OFF_BGAT 20183040u
#define OFF_BSA  29521920u
#define OFF_BPA  29716480u
#define OFF_AV   29911040u   // av [5][300][10] f32 = 60000 B (el/er projection)
#define OFF_H16  32368640u   // [2304][312] bf16 (624B rows, cols 300..311 zero)
#define OFF_Z    33806336u   // [2304][3072] bf16 (cols 0..1499 fc, 1500..2999 res)
#define OFF_EL   47962112u
#define OFF_ER   48008192u
#define OFF_CNT  48054272u
#define OFF_CUR  48063488u
#define OFF_PTR  48072704u
#define OFF_EID  48082176u

// ---------------- mega pack: all weight repacks + av precompute ----------------
// ranges: [0,9375) wordW | [9375,11199) cnnB | [11199,29439) gatB |
//         [29439,29819) poolB sa | [29819,30199) poolB pa | [30199,30258) av
__device__ __forceinline__ void pool_pack_body(const float* __restrict__ W,
    unsigned short* __restrict__ out, int i) {
  if (i >= 97280) return;
  int nt = i / (19 * 512);
  int r2 = i - nt * (19 * 512);
  int ks = r2 >> 9;
  int lr = r2 & 511;
  int lane = lr >> 3, j = lr & 7;
  int col = nt * 32 + (lane & 31);
  int k = ks * 16 + 8 * (lane >> 5) + j;
  float v = 0.f;
  if (k < 300 && col < 300) v = W[k * 300 + col];
  out[i] = f2b(v);
}

__global__ void mega_pack(
    const float* __restrict__ word_W,
    const float* __restrict__ w3, const float* __restrict__ w4, const float* __restrict__ w5,
    const float* __restrict__ fc, const float* __restrict__ res,
    const float* __restrict__ al, const float* __restrict__ ar,
    const float* __restrict__ sa_W, const float* __restrict__ pa_W,
    unsigned short* __restrict__ wW16, unsigned short* __restrict__ Bcnn,
    unsigned short* __restrict__ Bgat, unsigned short* __restrict__ Bsa,
    unsigned short* __restrict__ Bpa, float* __restrict__ av) {
  int blk = blockIdx.x, tid = threadIdx.x;
  if (blk < 9375) {
    int i4 = (blk * 256 + tid) * 4;
    if (i4 >= 9600000) return;
    const float4 v = *(const float4*)(word_W + i4);
    uint2 o;
    o.x = (unsigned int)f2b(v.x) | ((unsigned int)f2b(v.y) << 16);
    o.y = (unsigned int)f2b(v.z) | ((unsigned int)f2b(v.w) << 16);
    *(uint2*)(wW16 + i4) = o;
  } else if (blk < 11199) {
    int i = (blk - 9375) * 256 + tid;
    if (i >= 466944) return;
    int width, local; const float* cw;
    if (i < 116736)      { width = 3; local = i;          cw = w3; }
    else if (i < 272384) { width = 4; local = i - 116736; cw = w4; }
    else                 { width = 5; local = i - 272384; cw = w5; }
    int KS = 19 * width;
    int per_nt = KS * 512;
    int nt = local / per_nt;
    int rem = local - nt * per_nt;
    int ks = rem >> 9;
    int lr = rem & 511;
    int lane = lr >> 3, j = lr & 7;
    int col = nt * 32 + (lane & 31);
    int k = ks * 16 + 8 * (lane >> 5) + j;
    int tap = k / 304, koff = k - tap * 304;
    float v = 0.f;
    if (col < 100 && koff < 300) v = cw[(col * width + tap) * 300 + koff];
    Bcnn[i] = f2b(v);
  } else if (blk < 29439) {
    int i = (blk - 11199) * 256 + tid;
    if (i >= 4669440) return;
    int layer = i / 933888;
    int rem = i - layer * 933888;
    int nt = rem / (19 * 512);
    int r2 = rem - nt * (19 * 512);
    int ks = r2 >> 9;
    int lr = r2 & 511;
    int lane = lr >> 3, j = lr & 7;
    int col = nt * 32 + (lane & 31);
    int k = ks * 16 + 8 * (lane >> 5) + j;
    float v = 0.f;
    if (k < 300) {
      if (col < 1500)      v = fc[((size_t)layer * 300 + k) * 1500 + col];
      else if (col < 3000) v = res[((size_t)layer * 300 + k) * 1500 + (col - 1500)];
    }
    Bgat[i] = f2b(v);
  } else if (blk < 29819) {
    pool_pack_body(sa_W, Bsa, (blk - 29439) * 256 + tid);
  } else if (blk < 30199) {
    pool_pack_body(pa_W, Bpa, (blk - 29819) * 256 + tid);
  } else {
    // av[l][k][o]: o<5 -> el head o (from al), o>=5 -> er head o-5 (from ar)
    int i = (blk - 30199) * 256 + tid;
    if (i >= 15000) return;
    int l = i / 3000;
    int r = i - l * 3000;
    int k = r / 10, o = r - k * 10;
    int h = (o < 5) ? o : (o - 5);
    const float* src = (o < 5) ? al : ar;
    const float* fr = fc + ((size_t)l * 300 + k) * 1500 + h * 300;
    const float* sr = src + (size_t)l * 1500 + h * 300;
    float acc = 0.f;
    for (int d = 0; d < 300; ++d) acc += fr[d] * sr[d];
    av[i] = acc;
  }
}

// ---------------- CSR build (single block, 1024 threads) ----------------
__global__ __launch_bounds__(1024) void csr_build(
    const int* __restrict__ dst, int* __restrict__ cnt, int* __restrict__ cur,
    int* __restrict__ ptr, int* __restrict__ eid) {
  __shared__ int part[256];
  __shared__ int loc[NNODE];
  int t = threadIdx.x;
  for (int i = t; i < NNODE; i += 1024) { cnt[i] = 0; cur[i] = 0; }
  __syncthreads();
  for (int e = t; e < NE; e += 1024) atomicAdd(&cnt[dst[e]], 1);
  __syncthreads();
  int s = 0;
  if (t < 256) {
    for (int k = 0; k < 9; ++k) { loc[t * 9 + k] = s; s += cnt[t * 9 + k]; }
    part[t] = s;
  }
  __syncthreads();
  for (int off = 1; off < 256; off <<= 1) {
    int add = (t < 256 && t >= off) ? part[t - off] : 0;
    __syncthreads();
    if (t < 256) part[t] += add;
    __syncthreads();
  }
  if (t < 256) {
    int base = part[t] - s;
    for (int k = 0; k < 9; ++k) ptr[t * 9 + k] = base + loc[t * 9 + k];
    if (t == 255) ptr[NNODE] = part[255];
  }
  __syncthreads();
  for (int e = t; e < NE; e += 1024) {
    int d = dst[e];
    int pos = atomicAdd(&cur[d], 1);
    eid[ptr[d] + pos] = e;
  }
}

// ---------------- CNN ----------------
// LDS: A [256 rows][624 B stride] = 159744 (odd multiple of 16 -> conflict-free)
// scratch 8 waves * 64 f32 @159744 -> 161792
// 8 waves = 4 Mblk (64 rows) x 2 nt-pairs (64 cols). Wave: acc[2M][2N].
// B: depth-6 register ring (R6 config, 673us/32.6% MfmaUtil — best known;
// A-side prefetch attempts collapse the compiler's ring allocation, R7).
// Epilogue fused: writes h16 row directly (bias + posW), wx eliminated.
template<int W, int WSEC>
__device__ __forceinline__ void cnn_section(const char* sm, float* scratch,
    const unsigned short* Bsec, const float* bias, const float* posrow,
    unsigned short* hrow, int tid) {
  const int KS = 19 * W;
  const int PD = 6;   // prefetch depth
  int lane = tid & 63, wave = tid >> 6;
  int l31 = lane & 31, g = lane >> 5;
  int Mblk = wave >> 1, ntp = wave & 1;
  float16 acc[2][2] = {};
  const char* bbase = (const char*)Bsec + (size_t)(ntp * 2 * KS) * 1024 + lane * 16;
  short8 pb0[PD], pb1[PD];
  #pragma unroll
  for (int p = 0; p < PD; ++p) {
    pb0[p] = *(const short8*)(bbase + (size_t)p * 1024);
    pb1[p] = *(const short8*)(bbase + (size_t)(KS + p) * 1024);
  }
  int rbase = Mblk * 64 + l31;
  int ks = 0;
  #pragma unroll
  for (int j = 0; j < W; ++j) {
    int q0 = rbase + j;       q0 = (q0 > 255 ? 255 : q0) * 624;
    int q1 = rbase + 32 + j;  q1 = (q1 > 255 ? 255 : q1) * 624;
    #pragma unroll
    for (int kl = 0; kl < 19; ++kl) {
      int kb = kl * 32 + 16 * g;
      short8 a0 = *(const short8*)(sm + q0 + kb);
      short8 a1 = *(const short8*)(sm + q1 + kb);
      short8 b0 = pb0[ks % PD];
      short8 b1 = pb1[ks % PD];
      if (ks + PD < KS) {
        pb0[ks % PD] = *(const short8*)(bbase + (size_t)(ks + PD) * 1024);
        pb1[ks % PD] = *(const short8*)(bbase + (size_t)(KS + ks + PD) * 1024);
      }
      ++ks;
      acc[0][0] = MFMA(a0, b0, acc[0][0]);
      acc[0][1] = MFMA(a0, b1, acc[0][1]);
      acc[1][0] = MFMA(a1, b0, acc[1][0]);
      acc[1][1] = MFMA(a1, b1, acc[1][1]);
    }
  }
  // col = ntp*64 + ni*32 + l31 ; row = Mblk*64 + mi*32 + (r&3)+8*(r>>2)+4*g
  float cm0 = -3.0e38f, cm1 = -3.0e38f;
  #pragma unroll
  for (int mi = 0; mi < 2; ++mi) {
    #pragma unroll
    for (int r = 0; r < 16; ++r) {
      int row = Mblk * 64 + mi * 32 + (r & 3) + 8 * (r >> 2) + 4 * g;
      if (row <= 256 - W) {
        float v0 = acc[mi][0][r], v1 = acc[mi][1][r];
        if (v0 > cm0) cm0 = v0;
        if (v1 > cm1) cm1 = v1;
      }
    }
  }
  cm0 = fmaxf(cm0, __shfl_xor(cm0, 32));
  cm1 = fmaxf(cm1, __shfl_xor(cm1, 32));
  if (lane < 32) {
    scratch[wave * 64 + l31]      = cm0;
    scratch[wave * 64 + 32 + l31] = cm1;
  }
  __syncthreads();
  if (tid < 128) {
    int f = tid;
    if (f < 100) {
      int ntp_f = f >> 6, rest = f & 63;   // f = ntp*64 + ni*32 + c
      float v =        scratch[(0 * 2 + ntp_f) * 64 + rest];
      v = fmaxf(v,     scratch[(1 * 2 + ntp_f) * 64 + rest]);
      v = fmaxf(v,     scratch[(2 * 2 + ntp_f) * 64 + rest]);
      v = fmaxf(v,     scratch[(3 * 2 + ntp_f) * 64 + rest]);
      int d = WSEC * 100 + f;
      hrow[d] = f2b(v + bias[f] + posrow[d]);
    }
  }
  __syncthreads();
}

__global__ __launch_bounds__(512, 2) void cnn_kernel(
    const int* __restrict__ x, const unsigned short* __restrict__ wW,
    const unsigned short* __restrict__ Bcnn,
    const float* __restrict__ cb3, const float* __restrict__ cb4, const float* __restrict__ cb5,
    const int* __restrict__ u_idx, const int* __restrict__ lid,
    const float* __restrict__ posW, unsigned short* __restrict__ h16) {
  extern __shared__ char sm[];
  int n = blockIdx.x, tid = threadIdx.x;
  float* scratch = (float*)(sm + 159744);
  const int* xr = x + n * 256;
  for (int i = tid; i < 19968; i += 512) {   // 256 rows * 78 chunks (8B) = 624 B/row
    int r = i / 78, c = i - r * 78;
    uint2 v; v.x = 0u; v.y = 0u;
    if (c < 75) {
      int tok = xr[r];
      v = *(const uint2*)((const char*)wW + (size_t)tok * 600 + c * 8);
    }
    *(uint2*)(sm + r * 624 + c * 8) = v;
  }
  __syncthreads();
  unsigned short* hrow = h16 + (size_t)u_idx[n] * 312;
  const float* posrow = posW + (size_t)lid[n] * 300;
  cnn_section<3, 0>(sm, scratch, Bcnn,           cb3, posrow, hrow, tid);
  cnn_section<4, 1>(sm, scratch, Bcnn + 116736,  cb4, posrow, hrow, tid);
  cnn_section<5, 2>(sm, scratch, Bcnn + 272384,  cb5, posrow, hrow, tid);
  if (tid < 12) hrow[300 + tid] = 0;
}

// ---------------- party feature assembly ----------------
__global__ void party_kernel(const float* __restrict__ partyW,
                             const int* __restrict__ pids, const int* __restrict__ q_idx,
                             unsigned short* __restrict__ h16) {
  int b = blockIdx.x, t = threadIdx.x;
  int node = q_idx[b];
  for (int d = t; d < 312; d += 64)
    h16[(size_t)node * 312 + d] =
        (d < 300) ? f2b(partyW[(size_t)pids[b] * 300 + d]) : (unsigned short)0;
}

// ---------------- GAT GEMM: z|res = h @ [fc|res] ----------------
__global__ __launch_bounds__(512, 2) void gat_mm(
    const unsigned short* __restrict__ h16, const unsigned short* __restrict__ Bg,
    unsigned short* __restrict__ z) {
  extern __shared__ char sm[];   // 128 rows * 624B = 79872
  int tid = threadIdx.x, lane = tid & 63, wave = tid >> 6;
  int WGm = blockIdx.x, WGn = blockIdx.y;
  const char* srcp = (const char*)h16 + (size_t)WGm * 79872;
  for (int i = tid; i < 4992; i += 512)
    *(uint4*)(sm + i * 16) = *(const uint4*)(srcp + (size_t)i * 16);
  __syncthreads();
  int l31 = lane & 31, g = lane >> 5;
  int Mblk = wave >> 2, Nblk = wave & 3;
  float16 acc[2][2] = {};
  const char* a0 = sm + (Mblk * 64 + l31) * 624 + 16 * g;
  const char* a1 = a0 + 32 * 624;
  const char* b0 = (const char*)Bg + (size_t)((WGn * 8 + Nblk * 2) * 19) * 1024 + lane * 16;
  const char* b1 = b0 + 19 * 1024;
  #pragma unroll 2
  for (int ks = 0; ks < 19; ++ks) {
    short8 A0 = *(const short8*)(a0 + ks * 32);
    short8 A1 = *(const short8*)(a1 + ks * 32);
    short8 B0 = *(const short8*)(b0 + (size_t)ks * 1024);
    short8 B1 = *(const short8*)(b1 + (size_t)ks * 1024);
    acc[0][0] = MFMA(A0, B0, acc[0][0]);
    acc[0][1] = MFMA(A0, B1, acc[0][1]);
    acc[1][0] = MFMA(A1, B0, acc[1][0]);
    acc[1][1] = MFMA(A1, B1, acc[1][1]);
  }
  #pragma unroll
  for (int mi = 0; mi < 2; ++mi)
    #pragma unroll
    for (int ni = 0; ni < 2; ++ni)
      #pragma unroll
      for (int r = 0; r < 16; ++r) {
        int row = WGm * 128 + Mblk * 64 + mi * 32 + (r & 3) + 8 * (r >> 2) + 4 * g;
        int col = WGn * 256 + (Nblk * 2 + ni) * 32 + l31;
        z[(size_t)row * 3072 + col] = f2b(acc[mi][ni][r]);
      }
}

// ---------------- GAT scores from h16 (replaces z-based edge1) ----------------
// el[n][h] = sum_k h[n][k] * av[k][h], er[n][h] = sum_k h[n][k] * av[k][5+h]
__global__ void gat_score(const unsigned short* __restrict__ h16,
                          const float* __restrict__ av,
                          float* __restrict__ el, float* __restrict__ er) {
  int node = blockIdx.x * 4 + (threadIdx.x >> 6);
  if (node >= NNODE) return;
  int lane = threadIdx.x & 63;
  float acc[10] = {};
  for (int c = 0; c < 5; ++c) {
    int k = c * 64 + lane;
    if (k < 300) {
      float hv = b2f(h16[(size_t)node * 312 + k]);
      const float* ap = av + k * 10;
      #pragma unroll
      for (int o = 0; o < 10; ++o) acc[o] += hv * ap[o];
    }
  }
  #pragma unroll
  for (int o = 0; o < 10; ++o)
    for (int s = 32; s; s >>= 1) acc[o] += __shfl_xor(acc[o], s);
  if (lane == 0) {
    for (int h = 0; h < 5; ++h) {
      el[node * 5 + h] = acc[h];
      er[node * 5 + h] = acc[5 + h];
    }
  }
}

__global__ __launch_bounds__(320) void gat_edge2(
    const unsigned short* __restrict__ z, const float* __restrict__ el,
    const float* __restrict__ er, const float* __restrict__ gb,
    const int* __restrict__ ptr, const int* __restrict__ eidl,
    const int* __restrict__ srcA, unsigned short* __restrict__ h16out) {
  int dstn = blockIdx.x;
  int tid = threadIdx.x, h = tid >> 6, lane = tid & 63;
  __shared__ float lds5[5][304];
  int p0 = ptr[dstn], deg = ptr[dstn + 1] - p0;
  float ee = 0.f, den = 0.f;
  int sj = 0;
  if (deg > 0) {
    float s = -3.0e38f;
    if (lane < deg) {
      int e = eidl[p0 + lane];
      sj = srcA[e];
      float sv = el[sj * 5 + h] + er[dstn * 5 + h];
      s = (sv >= 0.f) ? sv : 0.2f * sv;
    }
    float m = s;
    for (int t = 32; t; t >>= 1) m = fmaxf(m, __shfl_xor(m, t));
    ee = (lane < deg) ? __expf(s - m) : 0.f;
    den = ee;
    for (int t = 32; t; t >>= 1) den += __shfl_xor(den, t);
  }
  for (int it = 0; it < 5; ++it) {
    int d = lane + it * 64;
    float acc = 0.f;
    if (deg > 0) {
      for (int e = 0; e < deg; ++e) {
        float w = __shfl(ee, e);
        int srow = __shfl(sj, e);
        if (d < 300) acc += w * b2f(z[(size_t)srow * 3072 + h * 300 + d]);
      }
      acc /= den;
    }
    if (d < 300) {
      float res = b2f(z[(size_t)dstn * 3072 + 1500 + h * 300 + d]);
      lds5[h][d] = acc + res + gb[h * 300 + d];
    }
  }
  __syncthreads();
  if (tid < 312) {
    float v = 0.f;
    if (tid < 300)
      v = 0.2f * (lds5[0][tid] + lds5[1][tid] + lds5[2][tid] + lds5[3][tid] + lds5[4][tid]);
    h16out[(size_t)dstn * 312 + tid] = (tid < 300) ? f2b(v) : (unsigned short)0;
  }
}

// ---------------- pooling + head ----------------
__device__ __forceinline__ void ctx_attn(const char* XB, int mtiles, int Kvalid,
    const unsigned short* Bw, const float* bias, const float* cvec,
    float* T, float* AA, float* OUT, int tid) {
  int lane = tid & 63, wave = tid >> 6;
  int l31 = lane & 31, g = lane >> 5;
  int ntasks = mtiles * 10;
  for (int t = wave; t < ntasks; t += 8) {
    int nt, mt;
    if (mtiles == 2) { nt = t >> 1; mt = t & 1; } else { nt = t; mt = 0; }
    float16 acc = {};
    const char* ap = XB + (mt * 32 + l31) * 624 + 16 * g;
    const char* bp = (const char*)Bw + (size_t)(nt * 19) * 1024 + lane * 16;
    for (int ks = 0; ks < 19; ++ks) {
      short8 A = *(const short8*)(ap + ks * 32);
      short8 Bv = *(const short8*)(bp + (size_t)ks * 1024);
      acc = MFMA(A, Bv, acc);
    }
    int col = nt * 32 + l31;
    if (col < 300) {
      float bc = bias[col];
      #pragma unroll
      for (int r = 0; r < 16; ++r) {
        int row = mt * 32 + (r & 3) + 8 * (r >> 2) + 4 * g;
        T[row * 305 + col] = tanhf(acc[r] + bc);
      }
    }
  }
  __syncthreads();
  if (tid < 64) {
    float lg = -3.0e38f;
    if (tid < Kvalid) {
      lg = 0.f;
      for (int d = 0; d < 300; ++d) lg += T[tid * 305 + d] * cvec[d];
    }
    AA[tid] = lg;
  }
  __syncthreads();
  if (wave == 0) {
    float v = AA[lane];
    float m = v;
    for (int s2 = 32; s2; s2 >>= 1) m = fmaxf(m, __shfl_xor(m, s2));
    float e = (lane < Kvalid) ? __expf(v - m) : 0.f;
    float s = e;
    for (int s2 = 32; s2; s2 >>= 1) s += __shfl_xor(s, s2);
    AA[lane] = e / s;
  }
  __syncthreads();
  if (tid < 300) {
    float acc = 0.f;
    for (int k = 0; k < Kvalid; ++k)
      acc += AA[k] * b2f(*(const unsigned short*)(XB + k * 624 + tid * 2));
    OUT[tid] = acc;
  }
  __syncthreads();
}

__global__ __launch_bounds__(512) void pool_kernel(
    const unsigned short* __restrict__ h16,
    const int* __restrict__ u_idx, const int* __restrict__ q_idx,
    const float* __restrict__ py,
    const unsigned short* __restrict__ Bsa, const unsigned short* __restrict__ Bpa,
    const float* __restrict__ sab, const float* __restrict__ sac,
    const float* __restrict__ pab, const float* __restrict__ pac,
    const float* __restrict__ vW, const float* __restrict__ vb,
    const float* __restrict__ outW, const float* __restrict__ outb,
    float* __restrict__ dout) {
  extern __shared__ char sm[];
  int b = blockIdx.x, tid = threadIdx.x;
  char* HU = sm;                       // 39936
  char* HQ = sm + 39936;               // 19968 -> 59904
  float* T   = (float*)(sm + 59904);   // 64*305*4 = 78080 -> 137984
  float* AA  = (float*)(sm + 137984);  // 256 -> 138240
  float* PX  = (float*)(sm + 138240);  // 1216 -> 139456
  float* SX  = (float*)(sm + 139456);  // 1216 -> 140672
  float* RED = (float*)(sm + 140672);  // 2048 -> 142720
  for (int i = tid; i < 64 * 78; i += 512) {
    int r = i / 78, c = i - r * 78;
    int node = u_idx[b * 64 + r];
    *(uint2*)(HU + r * 624 + c * 8) =
        *(const uint2*)((const char*)h16 + (size_t)node * 624 + c * 8);
  }
  for (int i = tid; i < 32 * 78; i += 512) {
    int r = i / 78, c = i - r * 78;
    uint2 v; v.x = 0u; v.y = 0u;
    if (r < 8) {
      int node = q_idx[b * 8 + r];
      v = *(const uint2*)((const char*)h16 + (size_t)node * 624 + c * 8);
    }
    *(uint2*)(HQ + r * 624 + c * 8) = v;
  }
  __syncthreads();
  ctx_attn(HU, 2, 64, Bsa, sab, sac, T, AA, SX, tid);
  ctx_attn(HQ, 1, 8,  Bpa, pab, pac, T, AA, PX, tid);
  float contrib = 0.f;
  if (tid < 300) {
    float pv = py[b] * vW[tid] + vb[tid];
    contrib = PX[tid] * outW[tid] + SX[tid] * outW[300 + tid] + pv * outW[600 + tid];
  }
  RED[tid] = contrib;
  __syncthreads();
  for (int s = 256; s > 0; s >>= 1) {
    if (tid < s) RED[tid] += RED[tid + s];
    __syncthreads();
  }
  if (tid == 0) dout[b] = RED[0] + outb[0];
}

// ---------------- launcher ----------------
extern "C" void kernel_launch(void* const* d_in, const int* in_sizes, int n_in,
                              void* d_out, int out_size, void* d_ws, size_t ws_size,
                              hipStream_t stream) {
  (void)in_sizes; (void)n_in; (void)out_size; (void)ws_size;
  const int*   x       = (const int*)d_in[0];
  const int*   srcA    = (const int*)d_in[1];
  const int*   dstA    = (const int*)d_in[2];
  const int*   u_idx   = (const int*)d_in[3];
  const int*   q_idx   = (const int*)d_in[4];
  const int*   lid     = (const int*)d_in[5];
  const int*   pids    = (const int*)d_in[6];
  const float* py      = (const float*)d_in[7];
  const float* word_W  = (const float*)d_in[8];
  const float* cw3     = (const float*)d_in[9];
  const float* cb3     = (const float*)d_in[10];
  const float* cw4     = (const float*)d_in[11];
  const float* cb4     = (const float*)d_in[12];
  const float* cw5     = (const float*)d_in[13];
  const float* cb5     = (const float*)d_in[14];
  const float* party_W = (const float*)d_in[15];
  const float* pos_W   = (const float*)d_in[16];
  const float* gat_fc  = (const float*)d_in[17];
  const float* gat_al  = (const float*)d_in[18];
  const float* gat_ar  = (const float*)d_in[19];
  const float* gat_res = (const float*)d_in[20];
  const float* gat_b   = (const float*)d_in[21];
  const float* pa_W    = (const float*)d_in[22];
  const float* pa_b    = (const float*)d_in[23];
  const float* pa_c    = (const float*)d_in[24];
  const float* sa_W    = (const float*)d_in[25];
  const float* sa_b    = (const float*)d_in[26];
  const float* sa_c    = (const float*)d_in[27];
  const float* v_W     = (const float*)d_in[28];
  const float* v_b     = (const float*)d_in[29];
  const float* out_W   = (const float*)d_in[30];
  const float* out_b   = (const float*)d_in[31];

  char* ws = (char*)d_ws;
  unsigned short* wW16 = (unsigned short*)(ws + OFF_WW);
  unsigned short* Bcnn = (unsigned short*)(ws + OFF_BCNN);
  unsigned short* Bgat = (unsigned short*)(ws + OFF_BGAT);
  unsigned short* Bsa  = (unsigned short*)(ws + OFF_BSA);
  unsigned short* Bpa  = (unsigned short*)(ws + OFF_BPA);
  float*          av   = (float*)(ws + OFF_AV);
  unsigned short* h16  = (unsigned short*)(ws + OFF_H16);
  unsigned short* z    = (unsigned short*)(ws + OFF_Z);
  float*          el   = (float*)(ws + OFF_EL);
  float*          er   = (float*)(ws + OFF_ER);
  int*            cnt  = (int*)(ws + OFF_CNT);
  int*            cur  = (int*)(ws + OFF_CUR);
  int*            ptr  = (int*)(ws + OFF_PTR);
  int*            eid  = (int*)(ws + OFF_EID);

  (void)hipFuncSetAttribute((const void*)cnn_kernel,
      hipFuncAttributeMaxDynamicSharedMemorySize, 161792);
  (void)hipFuncSetAttribute((const void*)gat_mm,
      hipFuncAttributeMaxDynamicSharedMemorySize, 79872);
  (void)hipFuncSetAttribute((const void*)pool_kernel,
      hipFuncAttributeMaxDynamicSharedMemorySize, 142720);

  mega_pack<<<dim3(30258), dim3(256), 0, stream>>>(
      word_W, cw3, cw4, cw5, gat_fc, gat_res, gat_al, gat_ar, sa_W, pa_W,
      wW16, Bcnn, Bgat, Bsa, Bpa, av);
  csr_build<<<dim3(1), dim3(1024), 0, stream>>>(dstA, cnt, cur, ptr, eid);

  cnn_kernel<<<dim3(2048), dim3(512), 161792, stream>>>(
      x, wW16, Bcnn, cb3, cb4, cb5, u_idx, lid, pos_W, h16);
  party_kernel<<<dim3(256), dim3(64), 0, stream>>>(party_W, pids, q_idx, h16);

  for (int l = 0; l < 5; ++l) {
    gat_mm<<<dim3(18, 12), dim3(512), 79872, stream>>>(h16, Bgat + (size_t)l * 933888, z);
    gat_score<<<dim3(576), dim3(256), 0, stream>>>(h16, av + l * 3000, el, er);
    gat_edge2<<<dim3(NNODE), dim3(320), 0, stream>>>(z, el, er, gat_b + l * 1500,
                                                     ptr, eid, srcA, h16);
  }
  pool_kernel<<<dim3(32), dim3(512), 142720, stream>>>(
      h16, u_idx, q_idx, py, Bsa, Bpa, sa_b, sa_c, pa_b, pa_c,
      v_W, v_b, out_W, out_b, (float*)d_out);
}